// Round 6
// baseline (1176.347 us; speedup 1.0000x reference)
//
#include <hip/hip_runtime.h>

// SoilModelCQ: 2000-step sequential scan, 512 sites x 64 hidden buckets.
// Mapping: 1 wave per site (block=64), lane = hidden index. State in regs.
// Outputs (flat, concatenated): Q (NT,NS), C (NT,NS), S (NT,NS,NH),
// H1 (NT,NS,NH), H2 (NT,NS,NH), Qs (NT,NS,3).
//
// R1: shfl_xor -> DPP reductions (1482 -> 518 us/dispatch).
// R2/R3: SUB=10 reg-buffered burst stores -- NEUTRAL (524 us). VGPR=48
//     proves the machine scheduler re-interleaved (hoisted) the stores into
//     the compute loop to shorten live ranges, restoring the per-step vmcnt
//     WAR stall (~450 cy/step; VALUBusy 29.4% == pure-issue model).
// R4/R5: + sched_barrier(0) fences and 30-operand asm pin — never measured
//     (infra failed twice on this payload).
// R6: same experiment, smaller attack surface: DROP the 30-operand asm pin
//     (the scheduler motion R3 proved is machine-scheduler-level; the
//     sched_barrier(0) region boundaries alone forbid it), KEEP both
//     sched_barrier(0) fences around the store region.

constexpr int NT = 2000;
constexpr int NS = 512;
constexpr int NH = 64;
constexpr int CHUNK = 50;          // 2000 / 50 = 40 even chunks
constexpr int SUB = 10;            // steps buffered in regs before burst store

__device__ __forceinline__ float readlane_f(float v, int k) {
    return __int_as_float(__builtin_amdgcn_readlane(__float_as_int(v), k));
}

// v += dpp_move(v, CTRL); invalid source lanes contribute 0 (bound_ctrl=1).
template<int CTRL>
__device__ __forceinline__ float dpp_add(float v) {
    int sh = __builtin_amdgcn_update_dpp(0, __float_as_int(v), CTRL, 0xf, 0xf, true);
    return v + __int_as_float(sh);
}

__global__ void __launch_bounds__(64, 1)
soil_cq_kernel(const float* __restrict__ P, const float* __restrict__ T,
               const float* __restrict__ E,
               const float* __restrict__ w,  const float* __restrict__ wk1,
               const float* __restrict__ wk2, const float* __restrict__ we1,
               const float* __restrict__ we2, const float* __restrict__ wl,
               const float* __restrict__ wo,  const float* __restrict__ wc,
               float* __restrict__ out)
{
    const int site = blockIdx.x;   // 0..511
    const int lane = threadIdx.x;  // 0..63

    // ---- per-lane parameter precompute (once per wave) ----
    float wo_l = wo[lane];
    float mx = wo_l;
    #pragma unroll
    for (int off = 32; off; off >>= 1) mx = fmaxf(mx, __shfl_xor(mx, off));
    float ex = expf(wo_l - mx);
    float ssum = ex;
    #pragma unroll
    for (int off = 32; off; off >>= 1) ssum += __shfl_xor(ssum, off);
    const float a   = ex / ssum;                       // softmax(wo)
    const float ew  = expf(w[lane]) + 1.0f;            // snow melt factor
    const float sk1 = 1.0f / (1.0f + expf(-wk1[lane]));
    const float sk2 = 1.0f / (1.0f + expf(-wk2[lane]));
    const float se1 = 1.0f / (1.0f + expf(-we1[lane]));
    const float se2 = 1.0f / (1.0f + expf(-we2[lane]));
    const float L   = expf(wl[lane]);
    const float r   = 1.0f / sk2 / (1.0f + expf(wc[lane]));
    const float ar  = a * r;

    // ---- output pointers ----
    float* Qo  = out;
    float* Co  = out + (size_t)NT * NS;
    float* So  = out + (size_t)2 * NT * NS;
    float* H1o = So  + (size_t)NT * NS * NH;
    float* H2o = H1o + (size_t)NT * NS * NH;
    float* Qso = H2o + (size_t)NT * NS * NH;

    // lanes 0..4 each own one scalar output stream
    float* optr = nullptr;
    int    ostride = 0;
    if      (lane == 0) { optr = Qo  + site;                 ostride = NS;     }
    else if (lane == 1) { optr = Co  + site;                 ostride = NS;     }
    else if (lane == 2) { optr = Qso + (size_t)site * 3;     ostride = NS * 3; }
    else if (lane == 3) { optr = Qso + (size_t)site * 3 + 1; ostride = NS * 3; }
    else if (lane == 4) { optr = Qso + (size_t)site * 3 + 2; ostride = NS * 3; }

    float s = 0.f, h1 = 0.f, h2 = 0.f;
    size_t sidx = (size_t)site * NH + lane;     // index into S/H1/H2, +NS*NH per step
    const size_t STEP = (size_t)NS * NH;

    // ---- forcing prefetch: lane l holds timestep (chunk*CHUNK + l) ----
    float pv = 0.f, tv = 0.f, evv = 0.f;
    if (lane < CHUNK) {
        const size_t fb = (size_t)lane * NS + site;
        pv = P[fb]; tv = T[fb]; evv = E[fb];
    }

    for (int cb = 0; cb < NT / CHUNK; ++cb) {
        // prefetch next chunk (latency hidden behind 50 steps of compute)
        float pn = 0.f, tn = 0.f, en = 0.f;
        if (cb + 1 < NT / CHUNK && lane < CHUNK) {
            const size_t fb = ((size_t)(cb + 1) * CHUNK + lane) * NS + site;
            pn = P[fb]; tn = T[fb]; en = E[fb];
        }

        for (int kb = 0; kb < CHUNK / SUB; ++kb) {
            // per-step buffered outputs — all indices compile-time (full unroll)
            float sb[SUB], h1b[SUB], h2b[SUB];
            float T1[SUB], T2[SUB], T3[SUB];   // wave-uniform (post-readlane)

            #pragma unroll
            for (int j = 0; j < SUB; ++j) {
                const int k = kb * SUB + j;    // uniform runtime index — ok for readlane
                const float p = readlane_f(pv, k);
                const float t = readlane_f(tv, k);
                const float e = readlane_f(evv, k);

                const float tpos  = fmaxf(t, 0.f);
                const float psnow = (t < 0.f) ? p : 0.f;
                const float prain = (t > 0.f) ? p : 0.f;

                // SnowBucket
                const float smv  = tpos * ew;
                const float m    = fminf(smv, s);
                const float snew = s - m + psnow;
                const float x    = prain + m;
                // SoilBucket
                const float hh   = h1 + h2 + x;
                const float h1a  = fmaxf(hh - L, 0.f);
                const float q1   = h1a * sk1;
                const float h2a  = fminf(h1a + h2 + x, L);
                const float q2   = h2a * sk2;         // q3 == q2 in the reference
                const float e1   = e * se1;
                const float e2   = e * se2;
                const float h1n  = fmaxf(h1a - q1 - e1, 0.f);
                const float h2n  = fmaxf(h2a - q2 - e2 - q2, 0.f);

                sb[j]  = snew;
                h1b[j] = h1n;
                h2b[j] = h2n;

                // reductions over 64 hidden units — DPP (VALU latency),
                // off the carried-state critical path.
                float v1 = q1 * a;     // -> Qs1
                float v2 = q2 * a;     // -> Qs2
                float v3 = q2 * ar;    // -> sum(q2*a*r)
                v1 = dpp_add<0x111>(v1); v2 = dpp_add<0x111>(v2); v3 = dpp_add<0x111>(v3); // row_shr:1
                v1 = dpp_add<0x112>(v1); v2 = dpp_add<0x112>(v2); v3 = dpp_add<0x112>(v3); // row_shr:2
                v1 = dpp_add<0x114>(v1); v2 = dpp_add<0x114>(v2); v3 = dpp_add<0x114>(v3); // row_shr:4
                v1 = dpp_add<0x118>(v1); v2 = dpp_add<0x118>(v2); v3 = dpp_add<0x118>(v3); // row_shr:8
                v1 = dpp_add<0x142>(v1); v2 = dpp_add<0x142>(v2); v3 = dpp_add<0x142>(v3); // row_bcast:15
                v1 = dpp_add<0x143>(v1); v2 = dpp_add<0x143>(v2); v3 = dpp_add<0x143>(v3); // row_bcast:31

                T1[j] = readlane_f(v1, 63);
                T2[j] = readlane_f(v2, 63);
                T3[j] = readlane_f(v3, 63);

                s = snew; h1 = h1n; h2 = h2n;
            }

            // ---- region fence: stores below may not be scheduled into the
            // compute region above (this is the motion R3's VGPR=48 proved).
            __builtin_amdgcn_sched_barrier(0);

            // ---- burst store: 3*SUB coalesced 256B stores from distinct regs ----
            #pragma unroll
            for (int j = 0; j < SUB; ++j) {
                const size_t ix = sidx + (size_t)j * STEP;
                So[ix]  = sb[j];
                H1o[ix] = h1b[j];
                H2o[ix] = h2b[j];
            }

            // ---- scalar streams: one scattered 4B store per step, lanes 0..4 ----
            if (lane < 5) {
                #pragma unroll
                for (int j = 0; j < SUB; ++j) {
                    const float Qk = T1[j] + T2[j];
                    const float c  = (T3[j] * (1.0f / NH) + 1e-5f) / (Qk + 1e-5f);
                    float oval = (lane == 0) ? Qk
                               : (lane == 1) ? c
                               : (lane == 2) ? T1[j]
                               : (lane == 3) ? T2[j]
                               : 0.f;                 // Qs[:,:,2] stays 0
                    *optr = oval;
                    optr += ostride;
                }
            }
            __builtin_amdgcn_sched_barrier(0);

            sidx += (size_t)SUB * STEP;
        }

        pv = pn; tv = tn; evv = en;
    }
}

extern "C" void kernel_launch(void* const* d_in, const int* in_sizes, int n_in,
                              void* d_out, int out_size, void* d_ws, size_t ws_size,
                              hipStream_t stream) {
    const float* P   = (const float*)d_in[0];
    const float* T   = (const float*)d_in[1];
    const float* E   = (const float*)d_in[2];
    const float* w   = (const float*)d_in[3];
    const float* wk1 = (const float*)d_in[4];
    const float* wk2 = (const float*)d_in[5];
    const float* we1 = (const float*)d_in[6];
    const float* we2 = (const float*)d_in[7];
    const float* wl  = (const float*)d_in[8];
    const float* wo  = (const float*)d_in[9];
    const float* wc  = (const float*)d_in[10];

    soil_cq_kernel<<<NS, 64, 0, stream>>>(P, T, E, w, wk1, wk2, we1, we2, wl,
                                          wo, wc, (float*)d_out);
}

// Round 7
// 1174.777 us; speedup vs baseline: 1.0013x; 1.0013x over previous
//
#include <hip/hip_runtime.h>

// SoilModelCQ: 2000-step sequential scan, 512 sites x 64 hidden buckets.
// Mapping: 2 waves per site (block=128), lane = hidden index. State in regs.
// Outputs (flat, concatenated): Q (NT,NS), C (NT,NS), S (NT,NS,NH),
// H1 (NT,NS,NH), H2 (NT,NS,NH), Qs (NT,NS,3).
//
// R1: shfl_xor -> DPP reductions (1482 -> 518 us/dispatch).
// R2/R3: SUB=10 reg-buffered burst stores -- NEUTRAL (524 us). Re-analysis:
//     buffers DID materialize (30 VGPR + T1-3 in SGPRs, 64->96); store
//     placement is irrelevant. Store-WAR theory dead.
// R6: sched_barrier fences -- REGRESSION (555 us): the scheduler's natural
//     interleave was beneficial. Fences removed.
// R7: parity-split waves. Wall is per-wave per-step issue+dep-latency
//     (VALUBusy 29.4% == 59% busy on each of 2 active SIMDs; 2 SIMDs idle).
//     The reduction/output work (~40 instrs/step: 18 DPP + readlanes +
//     stores) does NOT feed the s/h1/h2 recurrence (~20 instrs). So: both
//     waves redundantly run the recurrence (bitwise-identical), and step
//     k's reductions+stores are owned by wave (k&1). Halves per-wave
//     per-step work AND doubles active SIMDs. Zero sync, zero LDS,
//     disjoint writes.

constexpr int NT = 2000;
constexpr int NS = 512;
constexpr int NH = 64;
constexpr int CHUNK = 50;          // 2000 / 50 = 40 even chunks

__device__ __forceinline__ float readlane_f(float v, int k) {
    return __int_as_float(__builtin_amdgcn_readlane(__float_as_int(v), k));
}

// v += dpp_move(v, CTRL); invalid source lanes contribute 0 (bound_ctrl=1).
template<int CTRL>
__device__ __forceinline__ float dpp_add(float v) {
    int sh = __builtin_amdgcn_update_dpp(0, __float_as_int(v), CTRL, 0xf, 0xf, true);
    return v + __int_as_float(sh);
}

__global__ void __launch_bounds__(128, 1)
soil_cq_kernel(const float* __restrict__ P, const float* __restrict__ T,
               const float* __restrict__ E,
               const float* __restrict__ w,  const float* __restrict__ wk1,
               const float* __restrict__ wk2, const float* __restrict__ we1,
               const float* __restrict__ we2, const float* __restrict__ wl,
               const float* __restrict__ wo,  const float* __restrict__ wc,
               float* __restrict__ out)
{
    const int site = blockIdx.x;        // 0..511
    const int tid  = threadIdx.x;       // 0..127
    const int wid  = tid >> 6;          // 0 or 1: owns steps with (k&1)==wid
    const int lane = tid & 63;          // hidden index

    // ---- per-lane parameter precompute (once per wave; both waves identical) ----
    float wo_l = wo[lane];
    float mx = wo_l;
    #pragma unroll
    for (int off = 32; off; off >>= 1) mx = fmaxf(mx, __shfl_xor(mx, off));
    float ex = expf(wo_l - mx);
    float ssum = ex;
    #pragma unroll
    for (int off = 32; off; off >>= 1) ssum += __shfl_xor(ssum, off);
    const float a   = ex / ssum;                       // softmax(wo)
    const float ew  = expf(w[lane]) + 1.0f;            // snow melt factor
    const float sk1 = 1.0f / (1.0f + expf(-wk1[lane]));
    const float sk2 = 1.0f / (1.0f + expf(-wk2[lane]));
    const float se1 = 1.0f / (1.0f + expf(-we1[lane]));
    const float se2 = 1.0f / (1.0f + expf(-we2[lane]));
    const float L   = expf(wl[lane]);
    const float r   = 1.0f / sk2 / (1.0f + expf(wc[lane]));
    const float ar  = a * r;

    // ---- output pointers ----
    float* Qo  = out;
    float* Co  = out + (size_t)NT * NS;
    float* So  = out + (size_t)2 * NT * NS;
    float* H1o = So  + (size_t)NT * NS * NH;
    float* H2o = H1o + (size_t)NT * NS * NH;
    float* Qso = H2o + (size_t)NT * NS * NH;

    // lanes 0..4 of each wave own one scalar output stream; this wave's
    // streams start at timestep wid and advance 2 timesteps per owned step.
    float* optr = nullptr;
    int    ostride = 0;                 // per-timestep element stride
    if      (lane == 0) { optr = Qo  + site;                 ostride = NS;     }
    else if (lane == 1) { optr = Co  + site;                 ostride = NS;     }
    else if (lane == 2) { optr = Qso + (size_t)site * 3;     ostride = NS * 3; }
    else if (lane == 3) { optr = Qso + (size_t)site * 3 + 1; ostride = NS * 3; }
    else if (lane == 4) { optr = Qso + (size_t)site * 3 + 2; ostride = NS * 3; }
    if (optr) optr += (size_t)wid * ostride;
    const int ostride2 = 2 * ostride;   // advance per OWNED step

    float s = 0.f, h1 = 0.f, h2 = 0.f;
    size_t sidx = (size_t)site * NH + lane;     // S/H1/H2 index, +NS*NH per step
    const size_t STEP = (size_t)NS * NH;

    // ---- forcing prefetch: lane l holds timestep (chunk*CHUNK + l) ----
    float pv = 0.f, tv = 0.f, evv = 0.f;
    if (lane < CHUNK) {
        const size_t fb = (size_t)lane * NS + site;
        pv = P[fb]; tv = T[fb]; evv = E[fb];
    }

    for (int cb = 0; cb < NT / CHUNK; ++cb) {
        // prefetch next chunk (latency hidden behind 50 steps of compute)
        float pn = 0.f, tn = 0.f, en = 0.f;
        if (cb + 1 < NT / CHUNK && lane < CHUNK) {
            const size_t fb = ((size_t)(cb + 1) * CHUNK + lane) * NS + site;
            pn = P[fb]; tn = T[fb]; en = E[fb];
        }

        #pragma unroll 10
        for (int k = 0; k < CHUNK; ++k) {
            const float p = readlane_f(pv, k);
            const float t = readlane_f(tv, k);
            const float e = readlane_f(evv, k);

            // ---- recurrence (every wave, every step; bitwise identical) ----
            const float tpos  = fmaxf(t, 0.f);
            const float psnow = (t < 0.f) ? p : 0.f;
            const float prain = (t > 0.f) ? p : 0.f;

            const float smv  = tpos * ew;
            const float m    = fminf(smv, s);
            const float snew = s - m + psnow;
            const float x    = prain + m;

            const float hh   = h1 + h2 + x;
            const float h1a  = fmaxf(hh - L, 0.f);
            const float q1   = h1a * sk1;
            const float h2a  = fminf(h1a + h2 + x, L);
            const float q2   = h2a * sk2;         // q3 == q2 in the reference
            const float e1   = e * se1;
            const float e2   = e * se2;
            const float h1n  = fmaxf(h1a - q1 - e1, 0.f);
            const float h2n  = fmaxf(h2a - q2 - e2 - q2, 0.f);

            // ---- owned steps only: stores + reductions + scalar outputs ----
            if ((k & 1) == wid) {                 // wave-uniform branch
                So[sidx]  = snew;
                H1o[sidx] = h1n;
                H2o[sidx] = h2n;

                float v1 = q1 * a;     // -> Qs1
                float v2 = q2 * a;     // -> Qs2
                float v3 = q2 * ar;    // -> sum(q2*a*r)
                v1 = dpp_add<0x111>(v1); v2 = dpp_add<0x111>(v2); v3 = dpp_add<0x111>(v3); // row_shr:1
                v1 = dpp_add<0x112>(v1); v2 = dpp_add<0x112>(v2); v3 = dpp_add<0x112>(v3); // row_shr:2
                v1 = dpp_add<0x114>(v1); v2 = dpp_add<0x114>(v2); v3 = dpp_add<0x114>(v3); // row_shr:4
                v1 = dpp_add<0x118>(v1); v2 = dpp_add<0x118>(v2); v3 = dpp_add<0x118>(v3); // row_shr:8
                v1 = dpp_add<0x142>(v1); v2 = dpp_add<0x142>(v2); v3 = dpp_add<0x142>(v3); // row_bcast:15
                v1 = dpp_add<0x143>(v1); v2 = dpp_add<0x143>(v2); v3 = dpp_add<0x143>(v3); // row_bcast:31

                const float t1 = readlane_f(v1, 63);   // Qs1
                const float t2 = readlane_f(v2, 63);   // Qs2
                const float t3 = readlane_f(v3, 63);   // sum(q2*a*r)
                const float Qk = t1 + t2;
                const float c  = (t3 * (1.0f / NH) + 1e-5f) / (Qk + 1e-5f);

                if (lane < 5) {
                    float oval = (lane == 0) ? Qk
                               : (lane == 1) ? c
                               : (lane == 2) ? t1
                               : (lane == 3) ? t2
                               : 0.f;                 // Qs[:,:,2] stays 0
                    *optr = oval;
                    optr += ostride2;
                }
            }

            s = snew; h1 = h1n; h2 = h2n;
            sidx += STEP;
        }

        pv = pn; tv = tn; evv = en;
    }
}

extern "C" void kernel_launch(void* const* d_in, const int* in_sizes, int n_in,
                              void* d_out, int out_size, void* d_ws, size_t ws_size,
                              hipStream_t stream) {
    const float* P   = (const float*)d_in[0];
    const float* T   = (const float*)d_in[1];
    const float* E   = (const float*)d_in[2];
    const float* w   = (const float*)d_in[3];
    const float* wk1 = (const float*)d_in[4];
    const float* wk2 = (const float*)d_in[5];
    const float* we1 = (const float*)d_in[6];
    const float* we2 = (const float*)d_in[7];
    const float* wl  = (const float*)d_in[8];
    const float* wo  = (const float*)d_in[9];
    const float* wc  = (const float*)d_in[10];

    soil_cq_kernel<<<NS, 128, 0, stream>>>(P, T, E, w, wk1, wk2, we1, we2, wl,
                                           wo, wc, (float*)d_out);
}

// Round 9
// 1019.821 us; speedup vs baseline: 1.1535x; 1.1519x over previous
//
#include <hip/hip_runtime.h>

// SoilModelCQ: 2000-step scan, 512 sites x 64 hidden buckets.
// R1: DPP reductions (1482 -> 518 us). R3: burst stores NEUTRAL (524).
// R6: sched fences REGRESSION (555). R7: parity-split waves NEUTRAL (548).
// Invariant ~630 cy/step across all structures => fixed per-step stall,
// unhideable at 1-2 waves/SIMD. R8: checkpoint-replay. Phase 1: recurrence
// only (one wave/site), writes S/H1/H2 at 16 boundary rows (states ARE
// outputs -> zero workspace). Phase 2: 512x16 time-groups (32 waves/CU)
// replay 125 steps each with all stores+reductions; TLP hides the stall.
// R9: identical resubmit of R8 (round-8 bench was an infra failure).
// Benign-race note: phase-2 group g rewrites checkpoint row t0+124 with a
// bitwise-identical value while group g+1 may read it — same value either
// way; aligned 4B stores don't tear; phase1->phase2 ordered by stream.

constexpr int NT = 2000;
constexpr int NS = 512;
constexpr int NH = 64;
constexpr int K    = 125;   // steps per phase-2 group
constexpr int NGRP = 16;    // NT / K
constexpr int CH1  = 50;    // phase-1 forcing chunk (lane-held)
constexpr int CH2  = 25;    // phase-2 forcing chunk (lane-held)

__device__ __forceinline__ float readlane_f(float v, int k) {
    return __int_as_float(__builtin_amdgcn_readlane(__float_as_int(v), k));
}

template<int CTRL>
__device__ __forceinline__ float dpp_add(float v) {
    int sh = __builtin_amdgcn_update_dpp(0, __float_as_int(v), CTRL, 0xf, 0xf, true);
    return v + __int_as_float(sh);
}

// ---------------- Phase 1: recurrence only, boundary-row stores ----------
__global__ void __launch_bounds__(64, 1)
soil_phase1(const float* __restrict__ P, const float* __restrict__ T,
            const float* __restrict__ E,
            const float* __restrict__ w,  const float* __restrict__ wk1,
            const float* __restrict__ wk2, const float* __restrict__ we1,
            const float* __restrict__ we2, const float* __restrict__ wl,
            float* __restrict__ out)
{
    const int site = blockIdx.x;
    const int lane = threadIdx.x;

    const float ew  = expf(w[lane]) + 1.0f;
    const float sk1 = 1.0f / (1.0f + expf(-wk1[lane]));
    const float sk2 = 1.0f / (1.0f + expf(-wk2[lane]));
    const float se1 = 1.0f / (1.0f + expf(-we1[lane]));
    const float se2 = 1.0f / (1.0f + expf(-we2[lane]));
    const float L   = expf(wl[lane]);

    float* So  = out + (size_t)2 * NT * NS;
    float* H1o = So  + (size_t)NT * NS * NH;
    float* H2o = H1o + (size_t)NT * NS * NH;

    float s = 0.f, h1 = 0.f, h2 = 0.f;
    const size_t base = (size_t)site * NH + lane;
    const size_t STEP = (size_t)NS * NH;

    float pv = 0.f, tv = 0.f, evv = 0.f;
    if (lane < CH1) {
        const size_t fb = (size_t)lane * NS + site;
        pv = P[fb]; tv = T[fb]; evv = E[fb];
    }

    int nextCk = K - 1;   // boundary rows: 124, 249, ..., 1999

    for (int cb = 0; cb < NT / CH1; ++cb) {
        float pn = 0.f, tn = 0.f, en = 0.f;
        if (cb + 1 < NT / CH1 && lane < CH1) {
            const size_t fb = ((size_t)(cb + 1) * CH1 + lane) * NS + site;
            pn = P[fb]; tn = T[fb]; en = E[fb];
        }

        #pragma unroll 5
        for (int k = 0; k < CH1; ++k) {
            const int t = cb * CH1 + k;
            const float p = readlane_f(pv, k);
            const float tt = readlane_f(tv, k);
            const float e = readlane_f(evv, k);

            const float tpos  = fmaxf(tt, 0.f);
            const float psnow = (tt < 0.f) ? p : 0.f;
            const float prain = (tt > 0.f) ? p : 0.f;
            const float smv  = tpos * ew;
            const float m    = fminf(smv, s);
            const float snew = s - m + psnow;
            const float x    = prain + m;
            const float hh   = h1 + h2 + x;
            const float h1a  = fmaxf(hh - L, 0.f);
            const float q1   = h1a * sk1;
            const float h2a  = fminf(h1a + h2 + x, L);
            const float q2   = h2a * sk2;
            const float e1   = e * se1;
            const float e2   = e * se2;
            const float h1n  = fmaxf(h1a - q1 - e1, 0.f);
            const float h2n  = fmaxf(h2a - q2 - e2 - q2, 0.f);

            if (t == nextCk) {                     // 16 times total
                const size_t ix = (size_t)t * STEP + base;
                So[ix]  = snew;
                H1o[ix] = h1n;
                H2o[ix] = h2n;
                nextCk += K;
            }

            s = snew; h1 = h1n; h2 = h2n;
        }
        pv = pn; tv = tn; evv = en;
    }
}

// ---------------- Phase 2: parallel replay with full outputs -------------
__global__ void __launch_bounds__(256, 8)
soil_phase2(const float* __restrict__ P, const float* __restrict__ T,
            const float* __restrict__ E,
            const float* __restrict__ w,  const float* __restrict__ wk1,
            const float* __restrict__ wk2, const float* __restrict__ we1,
            const float* __restrict__ we2, const float* __restrict__ wl,
            const float* __restrict__ wo,  const float* __restrict__ wc,
            float* __restrict__ out)
{
    const int tid  = threadIdx.x;
    const int wid  = tid >> 6;                    // 0..3
    const int lane = tid & 63;
    const int gx   = blockIdx.x;                  // 0..2047
    const int site = gx & (NS - 1);
    const int grp  = (gx >> 9) * 4 + wid;         // 0..15
    const int t0   = grp * K;

    float wo_l = wo[lane];
    float mx = wo_l;
    #pragma unroll
    for (int off = 32; off; off >>= 1) mx = fmaxf(mx, __shfl_xor(mx, off));
    float ex = expf(wo_l - mx);
    float ssum = ex;
    #pragma unroll
    for (int off = 32; off; off >>= 1) ssum += __shfl_xor(ssum, off);
    const float a   = ex / ssum;
    const float ew  = expf(w[lane]) + 1.0f;
    const float sk1 = 1.0f / (1.0f + expf(-wk1[lane]));
    const float sk2 = 1.0f / (1.0f + expf(-wk2[lane]));
    const float se1 = 1.0f / (1.0f + expf(-we1[lane]));
    const float se2 = 1.0f / (1.0f + expf(-we2[lane]));
    const float L   = expf(wl[lane]);
    const float r   = 1.0f / sk2 / (1.0f + expf(wc[lane]));
    const float ar  = a * r;

    float* Qo  = out;
    float* Co  = out + (size_t)NT * NS;
    float* So  = out + (size_t)2 * NT * NS;
    float* H1o = So  + (size_t)NT * NS * NH;
    float* H2o = H1o + (size_t)NT * NS * NH;
    float* Qso = H2o + (size_t)NT * NS * NH;

    float* optr = nullptr;
    int    ostride = 0;
    if      (lane == 0) { optr = Qo  + site;                 ostride = NS;     }
    else if (lane == 1) { optr = Co  + site;                 ostride = NS;     }
    else if (lane == 2) { optr = Qso + (size_t)site * 3;     ostride = NS * 3; }
    else if (lane == 3) { optr = Qso + (size_t)site * 3 + 1; ostride = NS * 3; }
    else if (lane == 4) { optr = Qso + (size_t)site * 3 + 2; ostride = NS * 3; }
    if (optr) optr += (size_t)t0 * ostride;

    const size_t STEP = (size_t)NS * NH;
    const size_t base = (size_t)site * NH + lane;
    size_t sidx = (size_t)t0 * STEP + base;

    // checkpoint load (group 0 starts from zeros)
    float s = 0.f, h1 = 0.f, h2 = 0.f;
    if (grp != 0) {
        const size_t cx = (size_t)(t0 - 1) * STEP + base;
        s  = So[cx];
        h1 = H1o[cx];
        h2 = H2o[cx];
    }

    float pv = 0.f, tv = 0.f, evv = 0.f;
    if (lane < CH2) {
        const size_t fb = ((size_t)t0 + lane) * NS + site;
        pv = P[fb]; tv = T[fb]; evv = E[fb];
    }

    for (int cb = 0; cb < K / CH2; ++cb) {
        float pn = 0.f, tn = 0.f, en = 0.f;
        if (cb + 1 < K / CH2 && lane < CH2) {
            const size_t fb = ((size_t)t0 + (size_t)(cb + 1) * CH2 + lane) * NS + site;
            pn = P[fb]; tn = T[fb]; en = E[fb];
        }

        #pragma unroll 5
        for (int k = 0; k < CH2; ++k) {
            const float p = readlane_f(pv, k);
            const float t = readlane_f(tv, k);
            const float e = readlane_f(evv, k);

            const float tpos  = fmaxf(t, 0.f);
            const float psnow = (t < 0.f) ? p : 0.f;
            const float prain = (t > 0.f) ? p : 0.f;
            const float smv  = tpos * ew;
            const float m    = fminf(smv, s);
            const float snew = s - m + psnow;
            const float x    = prain + m;
            const float hh   = h1 + h2 + x;
            const float h1a  = fmaxf(hh - L, 0.f);
            const float q1   = h1a * sk1;
            const float h2a  = fminf(h1a + h2 + x, L);
            const float q2   = h2a * sk2;
            const float e1   = e * se1;
            const float e2   = e * se2;
            const float h1n  = fmaxf(h1a - q1 - e1, 0.f);
            const float h2n  = fmaxf(h2a - q2 - e2 - q2, 0.f);

            So[sidx]  = snew;
            H1o[sidx] = h1n;
            H2o[sidx] = h2n;

            float v1 = q1 * a;
            float v2 = q2 * a;
            float v3 = q2 * ar;
            v1 = dpp_add<0x111>(v1); v2 = dpp_add<0x111>(v2); v3 = dpp_add<0x111>(v3);
            v1 = dpp_add<0x112>(v1); v2 = dpp_add<0x112>(v2); v3 = dpp_add<0x112>(v3);
            v1 = dpp_add<0x114>(v1); v2 = dpp_add<0x114>(v2); v3 = dpp_add<0x114>(v3);
            v1 = dpp_add<0x118>(v1); v2 = dpp_add<0x118>(v2); v3 = dpp_add<0x118>(v3);
            v1 = dpp_add<0x142>(v1); v2 = dpp_add<0x142>(v2); v3 = dpp_add<0x142>(v3);
            v1 = dpp_add<0x143>(v1); v2 = dpp_add<0x143>(v2); v3 = dpp_add<0x143>(v3);

            const float t1 = readlane_f(v1, 63);
            const float t2 = readlane_f(v2, 63);
            const float t3 = readlane_f(v3, 63);
            const float Qk = t1 + t2;
            const float c  = (t3 * (1.0f / NH) + 1e-5f) / (Qk + 1e-5f);

            if (lane < 5) {
                float oval = (lane == 0) ? Qk
                           : (lane == 1) ? c
                           : (lane == 2) ? t1
                           : (lane == 3) ? t2
                           : 0.f;
                *optr = oval;
                optr += ostride;
            }

            s = snew; h1 = h1n; h2 = h2n;
            sidx += STEP;
        }
        pv = pn; tv = tn; evv = en;
    }
}

extern "C" void kernel_launch(void* const* d_in, const int* in_sizes, int n_in,
                              void* d_out, int out_size, void* d_ws, size_t ws_size,
                              hipStream_t stream) {
    const float* P   = (const float*)d_in[0];
    const float* T   = (const float*)d_in[1];
    const float* E   = (const float*)d_in[2];
    const float* w   = (const float*)d_in[3];
    const float* wk1 = (const float*)d_in[4];
    const float* wk2 = (const float*)d_in[5];
    const float* we1 = (const float*)d_in[6];
    const float* we2 = (const float*)d_in[7];
    const float* wl  = (const float*)d_in[8];
    const float* wo  = (const float*)d_in[9];
    const float* wc  = (const float*)d_in[10];

    soil_phase1<<<NS, 64, 0, stream>>>(P, T, E, w, wk1, wk2, we1, we2, wl,
                                       (float*)d_out);
    soil_phase2<<<NS * NGRP / 4, 256, 0, stream>>>(P, T, E, w, wk1, wk2, we1,
                                                   we2, wl, wo, wc,
                                                   (float*)d_out);
}